// Round 5
// baseline (28551.889 us; speedup 1.0000x reference)
//
#include <hip/hip_runtime.h>
#include <stdint.h>
#include <stddef.h>

// LSTM_63488206569533: B=128, T=1024, I=256, H=512, fp32 in/out.
// Persistent kernel: 256 WGs (8 batch-groups x 32 unit-slices), one per CU.
// R5: tag-in-band h exchange {tag32|2xbf16} (no producer drain, no flags),
//     speculative bulk issue + per-chunk divergent retry (no R4 flood),
//     LDS h-tile with per-chunk monotonic counters (progressive MFMA),
//     wave-local gate shuffle transpose, ZERO __syncthreads in the loop.

#define Bn   128
#define Tn   1024
#define In   256
#define Hn   512
#define XROW 264   // shorts per xtile row (256 + 8 pad)
#define HROW 260   // dwords per hlds row (256 + 4 pad)

typedef float f4 __attribute__((ext_vector_type(4)));
typedef short s8 __attribute__((ext_vector_type(8)));
typedef unsigned int u32;
typedef unsigned long long u64;
typedef u32 u32x4 __attribute__((ext_vector_type(4)));

static __device__ __forceinline__ short f2bf(float f) {
  union { float f; unsigned u; } v; v.f = f;
  unsigned u = v.u;
  return (short)((u + 0x7FFFu + ((u >> 16) & 1u)) >> 16);  // RNE
}
#define AL(p) __hip_atomic_load((p), __ATOMIC_RELAXED, __HIP_MEMORY_SCOPE_AGENT)

__global__ __launch_bounds__(256, 1)
void lstm_persist(const float* __restrict__ x,
                  const float* __restrict__ W_ih,
                  const float* __restrict__ W_hh,
                  const float* __restrict__ b_ih,
                  const float* __restrict__ b_hh,
                  const float* __restrict__ fc_w,
                  const float* __restrict__ fc_b,
                  float* __restrict__ out,
                  u64* __restrict__ hbuf)   // [2][8][16][256] tagged entries
{
  const int tid  = threadIdx.x;
  const int wave = tid >> 6;
  const int lane = tid & 63;
  const int n16  = lane & 15;
  const int q    = lane >> 4;
  const int G    = blockIdx.x & 7;    // batch group
  const int ns   = blockIdx.x >> 3;   // unit slice 0..31

  __shared__ short xtile[2][16][XROW];   // x_t bf16, double-buffered
  __shared__ u32   hlds[2][16][HROW];    // h_t 2xbf16/dword, double-buffered
  __shared__ int   chunkcnt[2][16];      // monotonic per-chunk counters

  if (tid < 32) chunkcnt[tid >> 4][tid & 15] = 0;

  // ---- wave-local gate mapping (verified in R4): col c=n16 -> gate c>>2,
  // unit (c&3); each wave covers units ns*16+wave*4+(0..3), all 4 gates.
  const int uu    = n16 & 3;
  const int gsel  = n16 >> 2;                 // gate idx (B) / batch sub-row (cell)
  const int ug_l  = ns * 16 + wave * 4 + uu;  // my cell's global unit
  const int bat_l = G * 16 + q * 4 + gsel;    // my cell's global batch

  s8 bfrag[24];
  {
    const int wrow = gsel * Hn + ug_l;        // gate-row in [0,4H)
#pragma unroll
    for (int kk = 0; kk < 24; ++kk) {
      const float* p = (kk < 8)
        ? (W_ih + (size_t)wrow * In + kk * 32 + q * 8)
        : (W_hh + (size_t)wrow * Hn + (kk - 8) * 32 + q * 8);
      f4 lo = ((const f4*)p)[0];
      f4 hi = ((const f4*)p)[1];
      s8 b;
      b[0]=f2bf(lo[0]); b[1]=f2bf(lo[1]); b[2]=f2bf(lo[2]); b[3]=f2bf(lo[3]);
      b[4]=f2bf(hi[0]); b[5]=f2bf(hi[1]); b[6]=f2bf(hi[2]); b[7]=f2bf(hi[3]);
      bfrag[kk] = b;
    }
  }

  const float bia = b_ih[ug_l]        + b_hh[ug_l];
  const float bfa = b_ih[Hn   + ug_l] + b_hh[Hn   + ug_l];
  const float bga = b_ih[2*Hn + ug_l] + b_hh[2*Hn + ug_l];
  const float boa = b_ih[3*Hn + ug_l] + b_hh[3*Hn + ug_l];

  // ---- staging role: thread (em,en) stages batch em / chunk en (32 units)
  const int em = tid >> 4;     // 0..15 (== wave*4+q)
  const int en = tid & 15;     // 0..15

  const float* xbase = x + (size_t)(G * 16 + em) * Tn * In + en * 16;

  // ---- prologue: stage x_0; the ONLY barrier in the kernel ----
  {
    const f4* xp = (const f4*)xbase;
    f4 a = xp[0], b = xp[1], c = xp[2], d = xp[3];
    s8 lo, hi;
    lo[0]=f2bf(a[0]); lo[1]=f2bf(a[1]); lo[2]=f2bf(a[2]); lo[3]=f2bf(a[3]);
    lo[4]=f2bf(b[0]); lo[5]=f2bf(b[1]); lo[6]=f2bf(b[2]); lo[7]=f2bf(b[3]);
    hi[0]=f2bf(c[0]); hi[1]=f2bf(c[1]); hi[2]=f2bf(c[2]); hi[3]=f2bf(c[3]);
    hi[4]=f2bf(d[0]); hi[5]=f2bf(d[1]); hi[6]=f2bf(d[2]); hi[7]=f2bf(d[3]);
    s8* dst = (s8*)&xtile[0][em][en * 16];
    dst[0] = lo; dst[1] = hi;
  }
  __syncthreads();

  float creg = 0.f, hreg = 0.f;
  int tgt2[2] = {16, 16};

  for (int t = 0; t < Tn; ++t) {
    const int pr = t & 1, pw = pr ^ 1;
    const bool more = (t + 1 < Tn);
    f4 px0, px1, px2, px3;
    if (more) {  // prefetch x_{t+1} raw (consumed at step end)
      const f4* xp = (const f4*)(xbase + (size_t)(t + 1) * In);
      px0 = xp[0]; px1 = xp[1]; px2 = xp[2]; px3 = xp[3];
    }
    f4 accA = {0.f,0.f,0.f,0.f}, accB = {0.f,0.f,0.f,0.f};

    if (t > 0) {
      const u64 tagc = ((u64)(u32)t) << 32;
      const u64* hsrc = hbuf + (((size_t)pr * 8 + G) * 16 + em) * 256 + en * 16;
      u64 v[16];
#pragma unroll
      for (int i = 0; i < 16; ++i) v[i] = AL(hsrc + i);   // speculative, MLP
      const int tgt = tgt2[pr]; tgt2[pr] += 16;
      const int s0 = ns >> 1;   // own-WG chunk first (x-staging guarantee)
#pragma unroll 1
      for (int j = 0; j < 16; ++j) {
        const int s = (s0 + j) & 15;
        if (en == s) {          // my chunk's turn: validate + stage to LDS
          for (;;) {
            u64 bad = 0;
#pragma unroll
            for (int i = 0; i < 16; ++i) bad |= (v[i] ^ tagc);
            if (!(u32)(bad >> 32)) break;
            __builtin_amdgcn_s_sleep(1);
#pragma unroll
            for (int i = 0; i < 16; ++i) v[i] = AL(hsrc + i);
          }
          u32x4* hd = (u32x4*)&hlds[pr][em][en * 16];
          u32x4 w0 = {(u32)v[ 0],(u32)v[ 1],(u32)v[ 2],(u32)v[ 3]};
          u32x4 w1 = {(u32)v[ 4],(u32)v[ 5],(u32)v[ 6],(u32)v[ 7]};
          u32x4 w2 = {(u32)v[ 8],(u32)v[ 9],(u32)v[10],(u32)v[11]};
          u32x4 w3 = {(u32)v[12],(u32)v[13],(u32)v[14],(u32)v[15]};
          hd[0]=w0; hd[1]=w1; hd[2]=w2; hd[3]=w3;
          __asm__ volatile("s_waitcnt lgkmcnt(0)" ::: "memory");
          __hip_atomic_fetch_add(&chunkcnt[pr][s], 1,
                                 __ATOMIC_RELAXED, __HIP_MEMORY_SCOPE_WORKGROUP);
        }
        while (__hip_atomic_load(&chunkcnt[pr][s], __ATOMIC_RELAXED,
                                 __HIP_MEMORY_SCOPE_WORKGROUP) < tgt) {}
        __asm__ volatile("" ::: "memory");
        s8 afr;
        { u32x4 aw = *(const u32x4*)&hlds[pr][n16][s * 16 + q * 4];
          __builtin_memcpy(&afr, &aw, 16); }
        if (j & 1) accB = __builtin_amdgcn_mfma_f32_16x16x32_bf16(afr, bfrag[8+s], accB, 0,0,0);
        else       accA = __builtin_amdgcn_mfma_f32_16x16x32_bf16(afr, bfrag[8+s], accA, 0,0,0);
        if (j == 0) {  // x_t staged by own WG (chunk s0 covers own waves)
#pragma unroll
          for (int kk = 0; kk < 8; ++kk) {
            s8 a = *(const s8*)&xtile[pr][n16][kk * 32 + q * 8];
            if (kk & 1) accB = __builtin_amdgcn_mfma_f32_16x16x32_bf16(a, bfrag[kk], accB, 0,0,0);
            else        accA = __builtin_amdgcn_mfma_f32_16x16x32_bf16(a, bfrag[kk], accA, 0,0,0);
          }
        }
      }
    } else {   // t == 0: h_0 == 0, x only (xtile[0] from prologue)
#pragma unroll
      for (int kk = 0; kk < 8; ++kk) {
        s8 a = *(const s8*)&xtile[0][n16][kk * 32 + q * 8];
        if (kk & 1) accB = __builtin_amdgcn_mfma_f32_16x16x32_bf16(a, bfrag[kk], accB, 0,0,0);
        else        accA = __builtin_amdgcn_mfma_f32_16x16x32_bf16(a, bfrag[kk], accA, 0,0,0);
      }
    }

    float acc4[4];
#pragma unroll
    for (int r = 0; r < 4; ++r) acc4[r] = accA[r] + accB[r];

    // ---- wave-local 4x4 gate transpose (verified R4) ----
    const int basel = (lane & 0x30) | uu;
    float zi = 0.f, zf = 0.f, zg = 0.f, zo = 0.f;
#pragma unroll
    for (int r = 0; r < 4; ++r) {
      float t0 = __shfl(acc4[r], basel,      64);
      float t1 = __shfl(acc4[r], basel + 4,  64);
      float t2 = __shfl(acc4[r], basel + 8,  64);
      float t3 = __shfl(acc4[r], basel + 12, 64);
      if (gsel == r) { zi = t0; zf = t1; zg = t2; zo = t3; }
    }
    zi += bia; zf += bfa; zg += bga; zo += boa;

    float gi = 1.f / (1.f + __expf(-zi));
    float gf = 1.f / (1.f + __expf(-zf));
    float gg = 2.f / (1.f + __expf(-2.f * zg)) - 1.f;
    float go = 1.f / (1.f + __expf(-zo));
    creg = gf * creg + gi * gg;
    float tc = 2.f / (1.f + __expf(-2.f * creg)) - 1.f;
    hreg = go * tc;

    if (more) {
      // stage x_{t+1} BEFORE posting tags (barrier-free induction)
      {
        s8 lo, hi;
        lo[0]=f2bf(px0[0]); lo[1]=f2bf(px0[1]); lo[2]=f2bf(px0[2]); lo[3]=f2bf(px0[3]);
        lo[4]=f2bf(px1[0]); lo[5]=f2bf(px1[1]); lo[6]=f2bf(px1[2]); lo[7]=f2bf(px1[3]);
        hi[0]=f2bf(px2[0]); hi[1]=f2bf(px2[1]); hi[2]=f2bf(px2[2]); hi[3]=f2bf(px2[3]);
        hi[4]=f2bf(px3[0]); hi[5]=f2bf(px3[1]); hi[6]=f2bf(px3[2]); hi[7]=f2bf(px3[3]);
        s8* dst = (s8*)&xtile[pw][em][en * 16];
        dst[0] = lo; dst[1] = hi;
      }
      __asm__ volatile("s_waitcnt lgkmcnt(0)" ::: "memory");
      // post tagged h_{t+1}: single 8B atomic store, no drain, no flag
      u32 hb = (u32)(unsigned short)f2bf(hreg);
      u32 ob = (u32)__shfl_xor((int)hb, 1, 64);
      if (!(uu & 1)) {
        u64 entry = (((u64)(u32)(t + 1)) << 32) | (u64)(hb | (ob << 16));
        u64* hw = hbuf + (((size_t)pw * 8 + G) * 16 + (q * 4 + gsel)) * 256
                       + (ns * 8 + wave * 2 + (uu >> 1));
        __hip_atomic_store(hw, entry, __ATOMIC_RELAXED, __HIP_MEMORY_SCOPE_AGENT);
      }
    }
  }

  // ---- epilogue: out[b] = sum_u hT[b,u] * fc_w[u] + fc_b ----
  float partial = hreg * fc_w[ug_l];
  partial += __shfl_xor(partial, 1, 64);
  partial += __shfl_xor(partial, 2, 64);
  if (uu == 0) {
    if (ns == 0 && wave == 0) partial += fc_b[0];
    atomicAdd(&out[bat_l], partial);
  }
}

extern "C" void kernel_launch(void* const* d_in, const int* in_sizes, int n_in,
                              void* d_out, int out_size, void* d_ws, size_t ws_size,
                              hipStream_t stream) {
  const float* x    = (const float*)d_in[0];
  const float* W_ih = (const float*)d_in[1];
  const float* W_hh = (const float*)d_in[2];
  const float* b_ih = (const float*)d_in[3];
  const float* b_hh = (const float*)d_in[4];
  const float* fc_w = (const float*)d_in[5];
  const float* fc_b = (const float*)d_in[6];
  float* out = (float*)d_out;

  u64* hbuf = (u64*)d_ws;   // 2 x 8 x 16 x 256 x 8 B = 512 KB tagged entries
  // 0xAA poison never matches a tag in [1,1024) -> no init needed.

  hipMemsetAsync(d_out, 0, Bn * sizeof(float), stream);

  lstm_persist<<<dim3(256), dim3(256), 0, stream>>>(
      x, W_ih, W_hh, b_ih, b_hh, fc_w, fc_b, out, hbuf);
}